// Round 14
// baseline (99.661 us; speedup 1.0000x reference)
//
#include <hip/hip_runtime.h>
#include <hip/hip_bf16.h>
#include <math.h>

#define Bn 4
#define Cn 64
#define Pn 4096   // 64*64
#define QT 64     // q-tile per block
#define PBK 64    // p-block per flash iteration (4 waves x 16 rows)
#define NITER 32  // 2048 / PBK  (each block owns a p-half)
#define LOG2E 1.4426950408889634f

typedef __attribute__((ext_vector_type(8))) short short8;   // 8 bf16 (MFMA K=32 A/B frag)
typedef __attribute__((ext_vector_type(4))) short short4v;  // 4 bf16 (MFMA K=16 A/B frag)
typedef __attribute__((ext_vector_type(4))) float float4v;  // MFMA C/D frag
typedef unsigned short bfu;

__device__ __forceinline__ bfu f2bf(float x) {
    unsigned u = __float_as_uint(x);
    u = (u + 0x7fffu + ((u >> 16) & 1u)) >> 16;   // RNE; inputs finite
    return (bfu)u;
}

// ---------------------------------------------------------------------------
// Prep (unchanged): 768 blocks, 16KB LDS.
//   blocks [0,512):   knorm -> bf16 Kpc [B][P][C]  and tiled Kcp2 [B][P/16][C][16p]
//   blocks [512,768): 3x3 zero-padded box-sum * log2(e) -> S [B][C][P]
// ---------------------------------------------------------------------------
__global__ __launch_bounds__(256) void prep_kernel(const float* __restrict__ fg,
                                                   bfu* __restrict__ Kpc,
                                                   bfu* __restrict__ Kcp2,
                                                   float* __restrict__ S) {
    __shared__ float shbuf[64 * 64];
    int t = threadIdx.x;
    if (blockIdx.x < 512) {
        float* tile  = shbuf;            // [64c][32p] stride 33
        float* rnorm = shbuf + 64 * 33;
        int b  = blockIdx.x >> 7;
        int p0 = (blockIdx.x & 127) << 5;
        const float* src = fg + (size_t)b * Cn * Pn + p0;
        #pragma unroll
        for (int i = 0; i < 8; ++i) {
            int idx = i * 256 + t;
            int c = idx >> 5, p = idx & 31;
            tile[c * 33 + p] = src[(size_t)c * Pn + p];
        }
        __syncthreads();
        if (t < 32) {
            float ss = 0.f;
            #pragma unroll
            for (int c = 0; c < 64; ++c) { float v = tile[c * 33 + t]; ss += v * v; }
            rnorm[t] = 1.0f / (sqrtf(ss) + 1e-8f);
        }
        __syncthreads();
        bfu* dpc = Kpc + ((size_t)b * Pn + p0) * Cn;
        #pragma unroll
        for (int i = 0; i < 8; ++i) {
            int idx = i * 256 + t;
            int p = idx >> 6, c = idx & 63;
            dpc[(size_t)p * Cn + c] = f2bf(tile[c * 33 + p] * rnorm[p]);
        }
        // tiled transpose layout: Kcp2[b][pt][c][pl], pt = p>>4, pl = p&15
        bfu* d2 = Kcp2 + ((size_t)b * 256 + (p0 >> 4)) * 1024;
        #pragma unroll
        for (int i = 0; i < 8; ++i) {
            int idx = i * 256 + t;
            int c = idx >> 5, p = idx & 31;
            d2[(size_t)(p >> 4) * 1024 + c * 16 + (p & 15)] =
                f2bf(tile[c * 33 + p] * rnorm[p]);
        }
    } else {
        float (*pl)[64] = (float(*)[64])shbuf;
        int bc = blockIdx.x - 512;
        const float* src = fg + (size_t)bc * Pn;
        float*       dst = S  + (size_t)bc * Pn;
        #pragma unroll
        for (int i = 0; i < 16; ++i) {
            int idx = i * 256 + t;
            pl[idx >> 6][idx & 63] = src[idx];
        }
        __syncthreads();
        #pragma unroll
        for (int i = 0; i < 16; ++i) {
            int idx = i * 256 + t;
            int h = idx >> 6, w = idx & 63;
            float s = 0.f;
            #pragma unroll
            for (int dh = -1; dh <= 1; ++dh) {
                int hh = h + dh;
                if (hh < 0 || hh >= 64) continue;
                #pragma unroll
                for (int dw = -1; dw <= 1; ++dw) {
                    int ww = w + dw;
                    if (ww < 0 || ww >= 64) continue;
                    s += pl[hh][ww];
                }
            }
            dst[idx] = s * LOG2E;
        }
    }
}

// ---------------------------------------------------------------------------
// Flash, zero-LDS K-loop, p-split (R14). 512 blocks x 256 thr (4 waves).
// grid: b=(i&7)>>1 (XCD-pair), ph=i&1 (p-half), qt=i>>3.
// Wave w owns p-rows [ph*2048 + pb*64 + 16w, +16) per iteration:
//   score: A = global Kpc rows, B = hoisted S frags (K=32 MFMA x8)
//   exp'd scores -> register K=16 A-frags; accum B = global Kcp2 frags.
// Block emits UNNORMALIZED O-partial (64c x 64q) + denominator partial.
// ---------------------------------------------------------------------------
__global__ __launch_bounds__(256, 3) void flash_kernel(const bfu* __restrict__ Kpc,
                                                       const bfu* __restrict__ Kcp2,
                                                       const float* __restrict__ S,
                                                       float* __restrict__ Opart,
                                                       float* __restrict__ Lpart) {
    // Sl [0,8192) bfu; epilogue Ol fp32 [2][64][66] = 33792 B overlays it
    __shared__ __align__(16) bfu smem[16896];
    __shared__ float wredl[4][QT];
    bfu* Sl = smem;

    int i  = blockIdx.x;
    int b  = (i & 7) >> 1;                       // XCD-pair locality
    int ph = i & 1;                              // p-half
    int qt = i >> 3;                             // [0,64)
    int q0 = qt * QT;
    int t  = threadIdx.x;
    int w = t >> 6, l = t & 63, lq = l & 15, quad = l >> 4;

    const float* Sg  = S    + (size_t)b * Cn * Pn;
    const bfu*   gpc = Kpc  + (size_t)b * Pn * Cn;
    const bfu*   gt  = Kcp2 + (size_t)b * 256 * 1024;   // [pt][c][pl]

    // Sl[q][c] = bf16(Sg[c][q0+q]) (S pre-scaled by log2e), XOR-swizzled rows
    {
        int c = t >> 2, qq = (t & 3) * 16;
        const float* sp = &Sg[(size_t)c * Pn + q0 + qq];
        int ch = c >> 3, cl = c & 7;
        #pragma unroll
        for (int v4 = 0; v4 < 4; ++v4) {
            float4 v = *(const float4*)(sp + v4 * 4);
            float vv[4] = {v.x, v.y, v.z, v.w};
            #pragma unroll
            for (int k = 0; k < 4; ++k) {
                int row = qq + v4 * 4 + k;
                Sl[row * 64 + ((ch ^ (row & 7)) << 3) + cl] = f2bf(vv[k]);
            }
        }
    }
    __syncthreads();   // Sl visible

    // hoist S B-frags: B[k=c][n=q], n=lq(+16nt), k=quad*8+j (+32ks)
    short8 bs[4][2];
    #pragma unroll
    for (int nt = 0; nt < 4; ++nt)
        #pragma unroll
        for (int ks = 0; ks < 2; ++ks) {
            int row = nt * 16 + lq;
            bs[nt][ks] = *(const short8*)&Sl[row * 64 + (((ks * 4 + quad) ^ (lq & 7)) << 3)];
        }

    float4v o[4][4];   // [nt][cb]: q = 16nt+4quad+r, c = 16cb+lq (wave-private p-partial)
    #pragma unroll
    for (int nt = 0; nt < 4; ++nt)
        #pragma unroll
        for (int cb = 0; cb < 4; ++cb) o[nt][cb] = (float4v){0.f, 0.f, 0.f, 0.f};
    float lacc[4] = {0.f, 0.f, 0.f, 0.f};

    // per-wave global base addresses (advance by pb*4096 elements each iter)
    const bfu* ap = gpc + ((size_t)ph * 2048 + 16 * w + lq) * Cn + quad * 8;     // score A
    const bfu* tp = gt + ((size_t)ph * 128 + w) * 1024 + lq * 16 + quad * 4;     // accum B

    // prologue: load pb=0 operands
    float4 a0 = *(const float4*)ap;
    float4 a1 = *(const float4*)(ap + 32);
    short4v kb[4];
    #pragma unroll
    for (int cb = 0; cb < 4; ++cb) kb[cb] = *(const short4v*)(tp + cb * 256);

    for (int pb = 0; pb < NITER; ++pb) {
        // ---- prefetch pb+1 operands ----
        float4 na0, na1;
        short4v nkb[4];
        if (pb + 1 < NITER) {
            const bfu* apn = ap + (size_t)(pb + 1) * PBK * Cn;
            na0 = *(const float4*)apn;
            na1 = *(const float4*)(apn + 32);
            const bfu* tpn = tp + (size_t)(pb + 1) * 4 * 1024;
            #pragma unroll
            for (int cb = 0; cb < 4; ++cb) nkb[cb] = *(const short4v*)(tpn + cb * 256);
        }

        // ---- score GEMM (K=32): D[m=p][n=q], 4 q-subtiles ----
        short8 af0 = *(short8*)&a0, af1 = *(short8*)&a1;
        float4v sc[4];
        #pragma unroll
        for (int nt = 0; nt < 4; ++nt) {
            float4v acc = (float4v){0.f, 0.f, 0.f, 0.f};
            acc = __builtin_amdgcn_mfma_f32_16x16x32_bf16(af0, bs[nt][0], acc, 0, 0, 0);
            acc = __builtin_amdgcn_mfma_f32_16x16x32_bf16(af1, bs[nt][1], acc, 0, 0, 0);
            sc[nt] = acc;
        }

        // ---- exp2 + denominator; pack E directly as K=16 A-frags ----
        short4v epk[4];
        #pragma unroll
        for (int nt = 0; nt < 4; ++nt) {
            float e0 = __builtin_amdgcn_exp2f(sc[nt][0]);
            float e1 = __builtin_amdgcn_exp2f(sc[nt][1]);
            float e2 = __builtin_amdgcn_exp2f(sc[nt][2]);
            float e3 = __builtin_amdgcn_exp2f(sc[nt][3]);
            lacc[nt] += (e0 + e1) + (e2 + e3);
            short4v ep = {(short)f2bf(e0), (short)f2bf(e1), (short)f2bf(e2), (short)f2bf(e3)};
            epk[nt] = ep;
        }

        // ---- accum GEMM (K=16): o'[q][c] += E · Kcp2 frags ----
        #pragma unroll
        for (int cb = 0; cb < 4; ++cb) {
            #pragma unroll
            for (int nt = 0; nt < 4; ++nt)
                o[nt][cb] = __builtin_amdgcn_mfma_f32_16x16x16bf16_1k(epk[nt], kb[cb], o[nt][cb], 0, 0, 0);
        }

        // rotate prefetched operands
        a0 = na0; a1 = na1;
        #pragma unroll
        for (int cb = 0; cb < 4; ++cb) kb[cb] = nkb[cb];
    }

    // ---- denominator: quad-reduce then stash per wave ----
    #pragma unroll
    for (int nt = 0; nt < 4; ++nt) {
        lacc[nt] += __shfl_xor(lacc[nt], 16);
        lacc[nt] += __shfl_xor(lacc[nt], 32);
    }
    if (quad == 0)
        #pragma unroll
        for (int nt = 0; nt < 4; ++nt) wredl[w][nt * 16 + lq] = lacc[nt];

    // ---- cross-wave combine via LDS overlay (waves 0,1 write; 2,3 add) ----
    float* Ol = (float*)smem;   // [2][64 c][66] fp32 = 33792 B
    __syncthreads();            // Sl reads done; wredl visible
    if (w < 2) {
        #pragma unroll
        for (int nt = 0; nt < 4; ++nt)
            #pragma unroll
            for (int cb = 0; cb < 4; ++cb)
                #pragma unroll
                for (int r = 0; r < 4; ++r)
                    Ol[(w * 64 + 16 * cb + lq) * 66 + nt * 16 + quad * 4 + r] = o[nt][cb][r];
    }
    __syncthreads();
    if (w >= 2) {
        #pragma unroll
        for (int nt = 0; nt < 4; ++nt)
            #pragma unroll
            for (int cb = 0; cb < 4; ++cb)
                #pragma unroll
                for (int r = 0; r < 4; ++r)
                    Ol[((w - 2) * 64 + 16 * cb + lq) * 66 + nt * 16 + quad * 4 + r] += o[nt][cb][r];
    }
    __syncthreads();

    // ---- emit unnormalized partials ----
    size_t slot = ((size_t)(b * 2 + ph) * 64 + qt);
    float* Op = Opart + slot * 4096;
    #pragma unroll
    for (int k = 0; k < 16; ++k) {
        int idx = k * 256 + t;
        int c = idx >> 6, q = idx & 63;
        Op[idx] = Ol[c * 66 + q] + Ol[(64 + c) * 66 + q];
    }
    if (t < 64)
        Lpart[slot * 64 + t] = ((wredl[0][t] + wredl[1][t]) + (wredl[2][t] + wredl[3][t]));
}

// ---------------------------------------------------------------------------
// Combine: out[c][qt*64+q] = (O0+O1)/(l0+l1).  256 blocks (b x qt) x 256 thr.
// ---------------------------------------------------------------------------
__global__ __launch_bounds__(256) void combine_kernel(const float* __restrict__ Opart,
                                                      const float* __restrict__ Lpart,
                                                      float* __restrict__ out) {
    int i = blockIdx.x;
    int b = i >> 6, qt = i & 63;
    size_t s0 = ((size_t)(b * 2 + 0) * 64 + qt);
    size_t s1 = ((size_t)(b * 2 + 1) * 64 + qt);
    const float* O0 = Opart + s0 * 4096;
    const float* O1 = Opart + s1 * 4096;
    __shared__ float linv[64];
    int t = threadIdx.x;
    if (t < 64) linv[t] = 1.0f / (Lpart[s0 * 64 + t] + Lpart[s1 * 64 + t]);
    __syncthreads();
    float* og = out + (size_t)b * Cn * Pn + qt * 64;
    #pragma unroll
    for (int k = 0; k < 16; ++k) {
        int idx = k * 256 + t;
        int c = idx >> 6, q = idx & 63;
        og[(size_t)c * Pn + q] = (O0[idx] + O1[idx]) * linv[q];
    }
}

// ---------------------------------------------------------------------------
extern "C" void kernel_launch(void* const* d_in, const int* in_sizes, int n_in,
                              void* d_out, int out_size, void* d_ws, size_t ws_size,
                              hipStream_t stream) {
    const float* fg = (const float*)d_in[0];
    float* out = (float*)d_out;
    bfu*   Kpc  = (bfu*)d_ws;                              // 2 MB  bf16 [B][P][C]
    bfu*   Kcp2 = Kpc + (size_t)Bn * Pn * Cn;              // 2 MB  bf16 [B][P/16][C][16]
    float* S    = (float*)(Kcp2 + (size_t)Bn * Pn * Cn);   // 4 MB  fp32 [B][C][P]
    float* Opart = S + (size_t)Bn * Cn * Pn;               // 8 MB  fp32 [B*2][64][4096]
    float* Lpart = Opart + (size_t)512 * 4096;             // 128KB fp32 [B*2][64][64]

    prep_kernel   <<<768, 256, 0, stream>>>(fg, Kpc, Kcp2, S);
    flash_kernel  <<<512, 256, 0, stream>>>(Kpc, Kcp2, S, Opart, Lpart);
    combine_kernel<<<256, 256, 0, stream>>>(Opart, Lpart, out);
}

// Round 15
// 93.139 us; speedup vs baseline: 1.0700x; 1.0700x over previous
//
#include <hip/hip_runtime.h>
#include <hip/hip_bf16.h>
#include <math.h>

#define Bn 4
#define Cn 64
#define Pn 4096   // 64*64
#define QT 64     // q-tile per block
#define PBK 128   // p-block per flash iteration
#define NITER (Pn / PBK)
#define LOG2E 1.4426950408889634f

typedef __attribute__((ext_vector_type(8))) short short8;   // 8 bf16 (MFMA K=32 A/B frag)
typedef __attribute__((ext_vector_type(4))) short short4v;  // 4 bf16 (MFMA K=16 A/B frag)
typedef __attribute__((ext_vector_type(4))) float float4v;  // MFMA C/D frag
typedef unsigned short bfu;

__device__ __forceinline__ bfu f2bf(float x) {
    unsigned u = __float_as_uint(x);
    u = (u + 0x7fffu + ((u >> 16) & 1u)) >> 16;   // RNE; inputs finite
    return (bfu)u;
}

// ---------------------------------------------------------------------------
// Prep (unchanged): 768 blocks, 16KB LDS.
//   blocks [0,512):   knorm -> bf16 Kpc [B][P][C]  and tiled Kcp2 [B][P/16][C][16p]
//   blocks [512,768): 3x3 zero-padded box-sum * log2(e) -> S [B][C][P]
// ---------------------------------------------------------------------------
__global__ __launch_bounds__(256) void prep_kernel(const float* __restrict__ fg,
                                                   bfu* __restrict__ Kpc,
                                                   bfu* __restrict__ Kcp2,
                                                   float* __restrict__ S) {
    __shared__ float shbuf[64 * 64];
    int t = threadIdx.x;
    if (blockIdx.x < 512) {
        float* tile  = shbuf;            // [64c][32p] stride 33
        float* rnorm = shbuf + 64 * 33;
        int b  = blockIdx.x >> 7;
        int p0 = (blockIdx.x & 127) << 5;
        const float* src = fg + (size_t)b * Cn * Pn + p0;
        #pragma unroll
        for (int i = 0; i < 8; ++i) {
            int idx = i * 256 + t;
            int c = idx >> 5, p = idx & 31;
            tile[c * 33 + p] = src[(size_t)c * Pn + p];
        }
        __syncthreads();
        if (t < 32) {
            float ss = 0.f;
            #pragma unroll
            for (int c = 0; c < 64; ++c) { float v = tile[c * 33 + t]; ss += v * v; }
            rnorm[t] = 1.0f / (sqrtf(ss) + 1e-8f);
        }
        __syncthreads();
        bfu* dpc = Kpc + ((size_t)b * Pn + p0) * Cn;
        #pragma unroll
        for (int i = 0; i < 8; ++i) {
            int idx = i * 256 + t;
            int p = idx >> 6, c = idx & 63;
            dpc[(size_t)p * Cn + c] = f2bf(tile[c * 33 + p] * rnorm[p]);
        }
        // tiled transpose layout: Kcp2[b][pt][c][pl], pt = p>>4, pl = p&15
        bfu* d2 = Kcp2 + ((size_t)b * 256 + (p0 >> 4)) * 1024;
        #pragma unroll
        for (int i = 0; i < 8; ++i) {
            int idx = i * 256 + t;
            int c = idx >> 5, p = idx & 31;
            d2[(size_t)(p >> 4) * 1024 + c * 16 + (p & 15)] =
                f2bf(tile[c * 33 + p] * rnorm[p]);
        }
    } else {
        float (*pl)[64] = (float(*)[64])shbuf;
        int bc = blockIdx.x - 512;
        const float* src = fg + (size_t)bc * Pn;
        float*       dst = S  + (size_t)bc * Pn;
        #pragma unroll
        for (int i = 0; i < 16; ++i) {
            int idx = i * 256 + t;
            pl[idx >> 6][idx & 63] = src[idx];
        }
        __syncthreads();
        #pragma unroll
        for (int i = 0; i < 16; ++i) {
            int idx = i * 256 + t;
            int h = idx >> 6, w = idx & 63;
            float s = 0.f;
            #pragma unroll
            for (int dh = -1; dh <= 1; ++dh) {
                int hh = h + dh;
                if (hh < 0 || hh >= 64) continue;
                #pragma unroll
                for (int dw = -1; dw <= 1; ++dw) {
                    int ww = w + dw;
                    if (ww < 0 || ww >= 64) continue;
                    s += pl[hh][ww];
                }
            }
            dst[idx] = s * LOG2E;
        }
    }
}

// ---------------------------------------------------------------------------
// Flash (R15 = R13 + prefetch distance 2). 256 blocks x 512 thr, QT=64,
// XCD swizzle, zero-LDS K-loop, no barriers.
// Wave w owns p-rows [16w,16w+16) of each 128-p block end-to-end:
//   score: A = global Kpc rows (dwordx4), B = hoisted S frags (K=32 MFMA x8)
//   exp'd scores -> register K=16 A-frags (C-layout == A-layout)
//   accum: B = global Kcp2 frags (dwordx2); operands staged 2 iters ahead
//   to cover L2/LLC latency (~600+ cyc).
// ---------------------------------------------------------------------------
__global__ __launch_bounds__(512, 1) void flash_kernel(const bfu* __restrict__ Kpc,
                                                       const bfu* __restrict__ Kcp2,
                                                       const float* __restrict__ S,
                                                       float* __restrict__ out) {
    // Sl lives in [0,8192) bfu; epilogue Ol fp32 [4][64][66] overlays all 67.5 KB
    __shared__ __align__(16) bfu smem[33792];
    __shared__ float wredl[8][QT];
    bfu* Sl = smem;

    int i  = blockIdx.x;
    int b  = (i & 7) >> 1;                       // XCD-pair locality
    int qt = ((i >> 3) << 1) | (i & 1);
    int q0 = qt * QT;
    int t  = threadIdx.x;
    int w = t >> 6, l = t & 63, lq = l & 15, quad = l >> 4;

    const float* Sg  = S    + (size_t)b * Cn * Pn;
    const bfu*   gpc = Kpc  + (size_t)b * Pn * Cn;
    const bfu*   gt  = Kcp2 + (size_t)b * 256 * 1024;   // [pt][c][pl]

    // Sl[q][c] = bf16(Sg[c][q0+q]) (S pre-scaled by log2e), XOR-swizzled rows
    {
        int c = t >> 3, qq = (t & 7) * 8;
        const float* sp = &Sg[(size_t)c * Pn + q0 + qq];
        float4 v0 = *(const float4*)sp;
        float4 v1 = *(const float4*)(sp + 4);
        float vv[8] = {v0.x, v0.y, v0.z, v0.w, v1.x, v1.y, v1.z, v1.w};
        int ch = c >> 3, cl = c & 7;
        #pragma unroll
        for (int k = 0; k < 8; ++k) {
            int row = qq + k;
            Sl[row * 64 + ((ch ^ (row & 7)) << 3) + cl] = f2bf(vv[k]);
        }
    }
    __syncthreads();   // Sl visible

    // hoist S B-frags: B[k=c][n=q], n=lq(+16nt), k=quad*8+j (+32ks)
    short8 bs[4][2];
    #pragma unroll
    for (int nt = 0; nt < 4; ++nt)
        #pragma unroll
        for (int ks = 0; ks < 2; ++ks) {
            int row = nt * 16 + lq;
            bs[nt][ks] = *(const short8*)&Sl[row * 64 + (((ks * 4 + quad) ^ (lq & 7)) << 3)];
        }

    float4v o[4][4];   // [nt][cb]: q = 16nt+4quad+r, c = 16cb+lq (wave-private p-partial)
    #pragma unroll
    for (int nt = 0; nt < 4; ++nt)
        #pragma unroll
        for (int cb = 0; cb < 4; ++cb) o[nt][cb] = (float4v){0.f, 0.f, 0.f, 0.f};
    float lacc[4] = {0.f, 0.f, 0.f, 0.f};

    // per-wave global addresses
    const bfu* ap = gpc + ((size_t)16 * w + lq) * Cn + quad * 8;           // score A rows
    const bfu* tp = gt + (size_t)w * 1024 + lq * 16 + quad * 4;            // accum B frags

    // prologue: stage pb=0 (slot 0) and pb=1 (slot 1)
    float4 pa0[2], pa1[2];
    short4v pkb[2][4];
    #pragma unroll
    for (int s = 0; s < 2; ++s) {
        const bfu* aps = ap + (size_t)s * PBK * Cn;
        pa0[s] = *(const float4*)aps;
        pa1[s] = *(const float4*)(aps + 32);
        const bfu* tps = tp + (size_t)s * 8 * 1024;
        #pragma unroll
        for (int cb = 0; cb < 4; ++cb) pkb[s][cb] = *(const short4v*)(tps + cb * 256);
    }

    #pragma unroll 2
    for (int pb = 0; pb < NITER; ++pb) {
        int s = pb & 1;

        // consume stage s into locals (register renames)
        float4 ca0 = pa0[s], ca1 = pa1[s];
        short4v ckb[4];
        #pragma unroll
        for (int cb = 0; cb < 4; ++cb) ckb[cb] = pkb[s][cb];

        // ---- refill stage s with pb+2 operands (distance-2 prefetch) ----
        if (pb + 2 < NITER) {
            const bfu* apn = ap + (size_t)(pb + 2) * PBK * Cn;
            pa0[s] = *(const float4*)apn;
            pa1[s] = *(const float4*)(apn + 32);
            const bfu* tpn = tp + (size_t)(pb + 2) * 8 * 1024;
            #pragma unroll
            for (int cb = 0; cb < 4; ++cb) pkb[s][cb] = *(const short4v*)(tpn + cb * 256);
        }

        // ---- score GEMM (K=32): D[m=p][n=q], 4 q-subtiles ----
        short8 af0 = *(short8*)&ca0, af1 = *(short8*)&ca1;
        float4v sc[4];
        #pragma unroll
        for (int nt = 0; nt < 4; ++nt) {
            float4v acc = (float4v){0.f, 0.f, 0.f, 0.f};
            acc = __builtin_amdgcn_mfma_f32_16x16x32_bf16(af0, bs[nt][0], acc, 0, 0, 0);
            acc = __builtin_amdgcn_mfma_f32_16x16x32_bf16(af1, bs[nt][1], acc, 0, 0, 0);
            sc[nt] = acc;
        }

        // ---- exp2 + denominator; pack E directly as K=16 A-frags ----
        short4v epk[4];
        #pragma unroll
        for (int nt = 0; nt < 4; ++nt) {
            float e0 = __builtin_amdgcn_exp2f(sc[nt][0]);
            float e1 = __builtin_amdgcn_exp2f(sc[nt][1]);
            float e2 = __builtin_amdgcn_exp2f(sc[nt][2]);
            float e3 = __builtin_amdgcn_exp2f(sc[nt][3]);
            lacc[nt] += (e0 + e1) + (e2 + e3);
            short4v ep = {(short)f2bf(e0), (short)f2bf(e1), (short)f2bf(e2), (short)f2bf(e3)};
            epk[nt] = ep;
        }

        // ---- accum GEMM (K=16): o'[q][c] += E · Kcp2 frags ----
        #pragma unroll
        for (int cb = 0; cb < 4; ++cb) {
            #pragma unroll
            for (int nt = 0; nt < 4; ++nt)
                o[nt][cb] = __builtin_amdgcn_mfma_f32_16x16x16bf16_1k(epk[nt], ckb[cb], o[nt][cb], 0, 0, 0);
        }
    }

    // ---- denominator: quad-reduce then stash per wave ----
    #pragma unroll
    for (int nt = 0; nt < 4; ++nt) {
        lacc[nt] += __shfl_xor(lacc[nt], 16);
        lacc[nt] += __shfl_xor(lacc[nt], 32);
    }
    if (quad == 0)
        #pragma unroll
        for (int nt = 0; nt < 4; ++nt) wredl[w][nt * 16 + lq] = lacc[nt];

    // ---- cross-wave combine via LDS overlay (2 rounds) ----
    float* Ol = (float*)smem;   // [4][64 c][66] fp32 = 67584 B
    __syncthreads();            // Sl reads done; wredl visible
    if (w < 4) {
        #pragma unroll
        for (int nt = 0; nt < 4; ++nt)
            #pragma unroll
            for (int cb = 0; cb < 4; ++cb)
                #pragma unroll
                for (int r = 0; r < 4; ++r)
                    Ol[(w * 64 + 16 * cb + lq) * 66 + nt * 16 + quad * 4 + r] = o[nt][cb][r];
    }
    __syncthreads();
    if (w >= 4) {
        #pragma unroll
        for (int nt = 0; nt < 4; ++nt)
            #pragma unroll
            for (int cb = 0; cb < 4; ++cb)
                #pragma unroll
                for (int r = 0; r < 4; ++r)
                    Ol[((w - 4) * 64 + 16 * cb + lq) * 66 + nt * 16 + quad * 4 + r] += o[nt][cb][r];
    }
    __syncthreads();

    // ---- final: out[c][q0+q] = sum of 4 buffers / l_q ----
    float* og = out + (size_t)b * Cn * Pn;
    #pragma unroll
    for (int k = 0; k < 8; ++k) {
        int idx = k * 512 + t;
        int c = idx >> 6, q = idx & 63;
        float lsum = ((wredl[0][q] + wredl[1][q]) + (wredl[2][q] + wredl[3][q])) +
                     ((wredl[4][q] + wredl[5][q]) + (wredl[6][q] + wredl[7][q]));
        float v = ((Ol[c * 66 + q] + Ol[(64 + c) * 66 + q]) +
                   (Ol[(128 + c) * 66 + q] + Ol[(192 + c) * 66 + q])) / lsum;
        og[(size_t)c * Pn + q0 + q] = v;
    }
}

// ---------------------------------------------------------------------------
extern "C" void kernel_launch(void* const* d_in, const int* in_sizes, int n_in,
                              void* d_out, int out_size, void* d_ws, size_t ws_size,
                              hipStream_t stream) {
    const float* fg = (const float*)d_in[0];
    float* out = (float*)d_out;
    bfu*   Kpc  = (bfu*)d_ws;                              // 2 MB  bf16 [B][P][C]
    bfu*   Kcp2 = Kpc + (size_t)Bn * Pn * Cn;              // 2 MB  bf16 [B][P/16][C][16]
    float* S    = (float*)(Kcp2 + (size_t)Bn * Pn * Cn);   // 4 MB  fp32 [B][C][P] (pre-scaled by log2e)

    prep_kernel <<<768, 256, 0, stream>>>(fg, Kpc, Kcp2, S);
    flash_kernel<<<Bn * 64, 512, 0, stream>>>(Kpc, Kcp2, S, out);
}

// Round 16
// 92.913 us; speedup vs baseline: 1.0726x; 1.0024x over previous
//
#include <hip/hip_runtime.h>
#include <hip/hip_bf16.h>
#include <math.h>

#define Bn 4
#define Cn 64
#define Pn 4096   // 64*64
#define QT 64     // q-tile per block
#define PBK 128   // p-block per flash iteration
#define NITER (Pn / PBK)
#define LOG2E 1.4426950408889634f

typedef __attribute__((ext_vector_type(8))) short short8;   // 8 bf16 (MFMA K=32 A/B frag)
typedef __attribute__((ext_vector_type(4))) short short4v;  // 4 bf16 (MFMA K=16 A/B frag)
typedef __attribute__((ext_vector_type(4))) float float4v;  // MFMA C/D frag
typedef unsigned short bfu;

__device__ __forceinline__ bfu f2bf(float x) {
    unsigned u = __float_as_uint(x);
    u = (u + 0x7fffu + ((u >> 16) & 1u)) >> 16;   // RNE; inputs finite
    return (bfu)u;
}

// ---------------------------------------------------------------------------
// Prep (unchanged): 768 blocks, 16KB LDS.
//   blocks [0,512):   knorm -> bf16 Kpc [B][P][C]  and tiled Kcp2 [B][P/16][C][16p]
//   blocks [512,768): 3x3 zero-padded box-sum * log2(e) -> S [B][C][P]
// ---------------------------------------------------------------------------
__global__ __launch_bounds__(256) void prep_kernel(const float* __restrict__ fg,
                                                   bfu* __restrict__ Kpc,
                                                   bfu* __restrict__ Kcp2,
                                                   float* __restrict__ S) {
    __shared__ float shbuf[64 * 64];
    int t = threadIdx.x;
    if (blockIdx.x < 512) {
        float* tile  = shbuf;            // [64c][32p] stride 33
        float* rnorm = shbuf + 64 * 33;
        int b  = blockIdx.x >> 7;
        int p0 = (blockIdx.x & 127) << 5;
        const float* src = fg + (size_t)b * Cn * Pn + p0;
        #pragma unroll
        for (int i = 0; i < 8; ++i) {
            int idx = i * 256 + t;
            int c = idx >> 5, p = idx & 31;
            tile[c * 33 + p] = src[(size_t)c * Pn + p];
        }
        __syncthreads();
        if (t < 32) {
            float ss = 0.f;
            #pragma unroll
            for (int c = 0; c < 64; ++c) { float v = tile[c * 33 + t]; ss += v * v; }
            rnorm[t] = 1.0f / (sqrtf(ss) + 1e-8f);
        }
        __syncthreads();
        bfu* dpc = Kpc + ((size_t)b * Pn + p0) * Cn;
        #pragma unroll
        for (int i = 0; i < 8; ++i) {
            int idx = i * 256 + t;
            int p = idx >> 6, c = idx & 63;
            dpc[(size_t)p * Cn + c] = f2bf(tile[c * 33 + p] * rnorm[p]);
        }
        // tiled transpose layout: Kcp2[b][pt][c][pl], pt = p>>4, pl = p&15
        bfu* d2 = Kcp2 + ((size_t)b * 256 + (p0 >> 4)) * 1024;
        #pragma unroll
        for (int i = 0; i < 8; ++i) {
            int idx = i * 256 + t;
            int c = idx >> 5, p = idx & 31;
            d2[(size_t)(p >> 4) * 1024 + c * 16 + (p & 15)] =
                f2bf(tile[c * 33 + p] * rnorm[p]);
        }
    } else {
        float (*pl)[64] = (float(*)[64])shbuf;
        int bc = blockIdx.x - 512;
        const float* src = fg + (size_t)bc * Pn;
        float*       dst = S  + (size_t)bc * Pn;
        #pragma unroll
        for (int i = 0; i < 16; ++i) {
            int idx = i * 256 + t;
            pl[idx >> 6][idx & 63] = src[idx];
        }
        __syncthreads();
        #pragma unroll
        for (int i = 0; i < 16; ++i) {
            int idx = i * 256 + t;
            int h = idx >> 6, w = idx & 63;
            float s = 0.f;
            #pragma unroll
            for (int dh = -1; dh <= 1; ++dh) {
                int hh = h + dh;
                if (hh < 0 || hh >= 64) continue;
                #pragma unroll
                for (int dw = -1; dw <= 1; ++dw) {
                    int ww = w + dw;
                    if (ww < 0 || ww >= 64) continue;
                    s += pl[hh][ww];
                }
            }
            dst[idx] = s * LOG2E;
        }
    }
}

// ---------------------------------------------------------------------------
// Flash (R16 = R13 + software-pipelined chain). 256 blocks x 512 thr, QT=64,
// XCD swizzle, zero-LDS, barrier-free K-loop.
// Modulo schedule: entering iter pb, sc(pb) is already computed; the body
// computes score(pb+1) (INDEPENDENT MFMA work) alongside exp(pb)->accum(pb),
// so the exp->accum dependency window is filled by construction.
// ---------------------------------------------------------------------------
__global__ __launch_bounds__(512, 1) void flash_kernel(const bfu* __restrict__ Kpc,
                                                       const bfu* __restrict__ Kcp2,
                                                       const float* __restrict__ S,
                                                       float* __restrict__ out) {
    // Sl lives in [0,8192) bfu; epilogue Ol fp32 [4][64][66] overlays all 67.5 KB
    __shared__ __align__(16) bfu smem[33792];
    __shared__ float wredl[8][QT];
    bfu* Sl = smem;

    int i  = blockIdx.x;
    int b  = (i & 7) >> 1;                       // XCD-pair locality
    int qt = ((i >> 3) << 1) | (i & 1);
    int q0 = qt * QT;
    int t  = threadIdx.x;
    int w = t >> 6, l = t & 63, lq = l & 15, quad = l >> 4;

    const float* Sg  = S    + (size_t)b * Cn * Pn;
    const bfu*   gpc = Kpc  + (size_t)b * Pn * Cn;
    const bfu*   gt  = Kcp2 + (size_t)b * 256 * 1024;   // [pt][c][pl]

    // Sl[q][c] = bf16(Sg[c][q0+q]) (S pre-scaled by log2e), XOR-swizzled rows
    {
        int c = t >> 3, qq = (t & 7) * 8;
        const float* sp = &Sg[(size_t)c * Pn + q0 + qq];
        float4 v0 = *(const float4*)sp;
        float4 v1 = *(const float4*)(sp + 4);
        float vv[8] = {v0.x, v0.y, v0.z, v0.w, v1.x, v1.y, v1.z, v1.w};
        int ch = c >> 3, cl = c & 7;
        #pragma unroll
        for (int k = 0; k < 8; ++k) {
            int row = qq + k;
            Sl[row * 64 + ((ch ^ (row & 7)) << 3) + cl] = f2bf(vv[k]);
        }
    }
    __syncthreads();   // Sl visible

    // hoist S B-frags: B[k=c][n=q], n=lq(+16nt), k=quad*8+j (+32ks)
    short8 bs[4][2];
    #pragma unroll
    for (int nt = 0; nt < 4; ++nt)
        #pragma unroll
        for (int ks = 0; ks < 2; ++ks) {
            int row = nt * 16 + lq;
            bs[nt][ks] = *(const short8*)&Sl[row * 64 + (((ks * 4 + quad) ^ (lq & 7)) << 3)];
        }

    float4v o[4][4];   // [nt][cb]: q = 16nt+4quad+r, c = 16cb+lq (wave-private p-partial)
    #pragma unroll
    for (int nt = 0; nt < 4; ++nt)
        #pragma unroll
        for (int cb = 0; cb < 4; ++cb) o[nt][cb] = (float4v){0.f, 0.f, 0.f, 0.f};
    float lacc[4] = {0.f, 0.f, 0.f, 0.f};

    // per-wave global addresses
    const bfu* ap = gpc + ((size_t)16 * w + lq) * Cn + quad * 8;           // score A rows
    const bfu* tp = gt + (size_t)w * 1024 + lq * 16 + quad * 4;            // accum B frags

    // ---- pipeline prologue ----
    // kb(0), a(1), kb(1) resident; sc(0) computed.
    float4 a00 = *(const float4*)ap;
    float4 a01 = *(const float4*)(ap + 32);
    short4v kbC[4];                                   // kb(pb)
    #pragma unroll
    for (int cb = 0; cb < 4; ++cb) kbC[cb] = *(const short4v*)(tp + cb * 256);
    const bfu* ap1 = ap + (size_t)PBK * Cn;
    float4 aN0 = *(const float4*)ap1;                 // a(pb+1)
    float4 aN1 = *(const float4*)(ap1 + 32);
    short4v kbN[4];                                   // kb(pb+1)
    #pragma unroll
    for (int cb = 0; cb < 4; ++cb) kbN[cb] = *(const short4v*)(tp + 8 * 1024 + cb * 256);

    float4v sc[4];                                    // sc(pb)
    {
        short8 af0 = *(short8*)&a00, af1 = *(short8*)&a01;
        #pragma unroll
        for (int nt = 0; nt < 4; ++nt) {
            float4v acc = (float4v){0.f, 0.f, 0.f, 0.f};
            acc = __builtin_amdgcn_mfma_f32_16x16x32_bf16(af0, bs[nt][0], acc, 0, 0, 0);
            acc = __builtin_amdgcn_mfma_f32_16x16x32_bf16(af1, bs[nt][1], acc, 0, 0, 0);
            sc[nt] = acc;
        }
    }

    // ---- steady state: iters 0..NITER-2 ----
    for (int pb = 0; pb < NITER - 1; ++pb) {
        // loads for pb+2
        float4 aF0, aF1;
        short4v kbF[4];
        if (pb + 2 < NITER) {
            const bfu* apn = ap + (size_t)(pb + 2) * PBK * Cn;
            aF0 = *(const float4*)apn;
            aF1 = *(const float4*)(apn + 32);
            const bfu* tpn = tp + (size_t)(pb + 2) * 8 * 1024;
            #pragma unroll
            for (int cb = 0; cb < 4; ++cb) kbF[cb] = *(const short4v*)(tpn + cb * 256);
        }

        // score(pb+1): independent MFMA work filling the exp->accum window
        float4v scN[4];
        {
            short8 af0 = *(short8*)&aN0, af1 = *(short8*)&aN1;
            #pragma unroll
            for (int nt = 0; nt < 4; ++nt) {
                float4v acc = (float4v){0.f, 0.f, 0.f, 0.f};
                acc = __builtin_amdgcn_mfma_f32_16x16x32_bf16(af0, bs[nt][0], acc, 0, 0, 0);
                acc = __builtin_amdgcn_mfma_f32_16x16x32_bf16(af1, bs[nt][1], acc, 0, 0, 0);
                scN[nt] = acc;
            }
        }

        // exp(pb) + denominator + pack as K=16 A-frags
        short4v epk[4];
        #pragma unroll
        for (int nt = 0; nt < 4; ++nt) {
            float e0 = __builtin_amdgcn_exp2f(sc[nt][0]);
            float e1 = __builtin_amdgcn_exp2f(sc[nt][1]);
            float e2 = __builtin_amdgcn_exp2f(sc[nt][2]);
            float e3 = __builtin_amdgcn_exp2f(sc[nt][3]);
            lacc[nt] += (e0 + e1) + (e2 + e3);
            short4v ep = {(short)f2bf(e0), (short)f2bf(e1), (short)f2bf(e2), (short)f2bf(e3)};
            epk[nt] = ep;
        }

        // accum(pb)
        #pragma unroll
        for (int cb = 0; cb < 4; ++cb) {
            #pragma unroll
            for (int nt = 0; nt < 4; ++nt)
                o[nt][cb] = __builtin_amdgcn_mfma_f32_16x16x16bf16_1k(epk[nt], kbC[cb], o[nt][cb], 0, 0, 0);
        }

        // rotate pipeline state
        #pragma unroll
        for (int nt = 0; nt < 4; ++nt) sc[nt] = scN[nt];
        #pragma unroll
        for (int cb = 0; cb < 4; ++cb) { kbC[cb] = kbN[cb]; kbN[cb] = kbF[cb]; }
        aN0 = aF0; aN1 = aF1;
    }

    // ---- epilogue iteration (pb = NITER-1): exp + accum only ----
    {
        short4v epk[4];
        #pragma unroll
        for (int nt = 0; nt < 4; ++nt) {
            float e0 = __builtin_amdgcn_exp2f(sc[nt][0]);
            float e1 = __builtin_amdgcn_exp2f(sc[nt][1]);
            float e2 = __builtin_amdgcn_exp2f(sc[nt][2]);
            float e3 = __builtin_amdgcn_exp2f(sc[nt][3]);
            lacc[nt] += (e0 + e1) + (e2 + e3);
            short4v ep = {(short)f2bf(e0), (short)f2bf(e1), (short)f2bf(e2), (short)f2bf(e3)};
            epk[nt] = ep;
        }
        #pragma unroll
        for (int cb = 0; cb < 4; ++cb) {
            #pragma unroll
            for (int nt = 0; nt < 4; ++nt)
                o[nt][cb] = __builtin_amdgcn_mfma_f32_16x16x16bf16_1k(epk[nt], kbC[cb], o[nt][cb], 0, 0, 0);
        }
    }

    // ---- denominator: quad-reduce then stash per wave ----
    #pragma unroll
    for (int nt = 0; nt < 4; ++nt) {
        lacc[nt] += __shfl_xor(lacc[nt], 16);
        lacc[nt] += __shfl_xor(lacc[nt], 32);
    }
    if (quad == 0)
        #pragma unroll
        for (int nt = 0; nt < 4; ++nt) wredl[w][nt * 16 + lq] = lacc[nt];

    // ---- cross-wave combine via LDS overlay (2 rounds) ----
    float* Ol = (float*)smem;   // [4][64 c][66] fp32 = 67584 B
    __syncthreads();            // Sl reads done; wredl visible
    if (w < 4) {
        #pragma unroll
        for (int nt = 0; nt < 4; ++nt)
            #pragma unroll
            for (int cb = 0; cb < 4; ++cb)
                #pragma unroll
                for (int r = 0; r < 4; ++r)
                    Ol[(w * 64 + 16 * cb + lq) * 66 + nt * 16 + quad * 4 + r] = o[nt][cb][r];
    }
    __syncthreads();
    if (w >= 4) {
        #pragma unroll
        for (int nt = 0; nt < 4; ++nt)
            #pragma unroll
            for (int cb = 0; cb < 4; ++cb)
                #pragma unroll
                for (int r = 0; r < 4; ++r)
                    Ol[((w - 4) * 64 + 16 * cb + lq) * 66 + nt * 16 + quad * 4 + r] += o[nt][cb][r];
    }
    __syncthreads();

    // ---- final: out[c][q0+q] = sum of 4 buffers / l_q ----
    float* og = out + (size_t)b * Cn * Pn;
    #pragma unroll
    for (int k = 0; k < 8; ++k) {
        int idx = k * 512 + t;
        int c = idx >> 6, q = idx & 63;
        float lsum = ((wredl[0][q] + wredl[1][q]) + (wredl[2][q] + wredl[3][q])) +
                     ((wredl[4][q] + wredl[5][q]) + (wredl[6][q] + wredl[7][q]));
        float v = ((Ol[c * 66 + q] + Ol[(64 + c) * 66 + q]) +
                   (Ol[(128 + c) * 66 + q] + Ol[(192 + c) * 66 + q])) / lsum;
        og[(size_t)c * Pn + q0 + q] = v;
    }
}

// ---------------------------------------------------------------------------
extern "C" void kernel_launch(void* const* d_in, const int* in_sizes, int n_in,
                              void* d_out, int out_size, void* d_ws, size_t ws_size,
                              hipStream_t stream) {
    const float* fg = (const float*)d_in[0];
    float* out = (float*)d_out;
    bfu*   Kpc  = (bfu*)d_ws;                              // 2 MB  bf16 [B][P][C]
    bfu*   Kcp2 = Kpc + (size_t)Bn * Pn * Cn;              // 2 MB  bf16 [B][P/16][C][16]
    float* S    = (float*)(Kcp2 + (size_t)Bn * Pn * Cn);   // 4 MB  fp32 [B][C][P] (pre-scaled by log2e)

    prep_kernel <<<768, 256, 0, stream>>>(fg, Kpc, Kcp2, S);
    flash_kernel<<<Bn * 64, 512, 0, stream>>>(Kpc, Kcp2, S, out);
}